// Round 5
// baseline (378.227 us; speedup 1.0000x reference)
//
#include <hip/hip_runtime.h>
#include <hip/hip_bf16.h>

// Problem constants
#define NB    32
#define DIM   512
#define HEADS 8
#define HD    64
#define NPIX  1024   // H*W = 32*32

typedef __bf16 bf16x8 __attribute__((ext_vector_type(8)));
typedef float  f32x4  __attribute__((ext_vector_type(4)));
typedef float  f32x16 __attribute__((ext_vector_type(16)));

union FragCast { int i[4]; bf16x8 v; };

__device__ __forceinline__ unsigned short f2bf(float f) {
    union { float f; unsigned int i; } x; x.f = f;
    unsigned int r = x.i + 0x7fffu + ((x.i >> 16) & 1u);
    return (unsigned short)(r >> 16);
}
__device__ __forceinline__ unsigned pkbf(float a, float b) {   // low16=a, hi16=b
    __hip_bfloat162 h = __float22bfloat162_rn(make_float2(a, b));
    union { __hip_bfloat162 h; unsigned u; } c; c.h = h; return c.u;
}
__device__ __forceinline__ void gl_lds16(const void* g, void* l) {
    __builtin_amdgcn_global_load_lds(
        (const __attribute__((address_space(1))) unsigned int*)g,
        (__attribute__((address_space(3))) unsigned int*)l, 16, 0, 0);
}

// ---------------------------------------------------------------------------
// Kernel W: wq fp32 [1536][512] -> wqb bf16 (contiguous convert)
// ---------------------------------------------------------------------------
__global__ __launch_bounds__(256) void k_prep_w(
        const float* __restrict__ wq, unsigned short* __restrict__ wqb) {
    const int idx = (blockIdx.x * 256 + threadIdx.x) * 4;
    float4 f = *(const float4*)(wq + idx);
    ushort4 u;
    u.x = f2bf(f.x); u.y = f2bf(f.y); u.z = f2bf(f.z); u.w = f2bf(f.w);
    *(ushort4*)(wqb + idx) = u;
}

// ---------------------------------------------------------------------------
// Kernel A: x fp32 [b][c][n] -> xt bf16 [b][n][c]  (64x64 LDS-tiled transpose)
// ---------------------------------------------------------------------------
__global__ __launch_bounds__(256) void k_transpose(
        const float* __restrict__ x, unsigned short* __restrict__ xt) {
    __shared__ unsigned short tile[64][68];
    const int t = threadIdx.x;
    const int lane4 = t & 15, grp = t >> 4;
    const int n0 = blockIdx.x * 64, c0 = blockIdx.y * 64, b = blockIdx.z;
    const size_t xb = (size_t)b * DIM * NPIX;
#pragma unroll
    for (int i = 0; i < 4; ++i) {
        int c = c0 + grp + i * 16;
        float4 f = *(const float4*)(x + xb + (size_t)c * NPIX + n0 + lane4 * 4);
        ushort4 u;
        u.x = f2bf(f.x); u.y = f2bf(f.y); u.z = f2bf(f.z); u.w = f2bf(f.w);
        *(ushort4*)&tile[grp + i * 16][lane4 * 4] = u;
    }
    __syncthreads();
    const size_t xtb = (size_t)b * NPIX * DIM;
#pragma unroll
    for (int i = 0; i < 4; ++i) {
        int nr = grp + i * 16;
        ushort4 v;
        v.x = tile[lane4 * 4 + 0][nr];
        v.y = tile[lane4 * 4 + 1][nr];
        v.z = tile[lane4 * 4 + 2][nr];
        v.w = tile[lane4 * 4 + 3][nr];
        *(ushort4*)(xt + xtb + (size_t)(n0 + nr) * DIM + c0 + lane4 * 4) = v;
    }
}

// ---------------------------------------------------------------------------
// Kernel B: QKV GEMM, double-buffered LDS, XOR-swizzled tiles (unchanged R4).
// ---------------------------------------------------------------------------
__global__ __launch_bounds__(256, 2) void k_qkv(
        const unsigned short* __restrict__ xt, const unsigned short* __restrict__ wqb,
        const float* __restrict__ bias,
        const float* __restrict__ hrel, const float* __restrict__ wrel,
        unsigned short* __restrict__ qs, unsigned short* __restrict__ ks,
        unsigned short* __restrict__ vt) {
    __shared__ unsigned short At[2][128 * 64];
    __shared__ unsigned short Bt[2][128 * 64];
    const int t = threadIdx.x;
    const int lane = t & 63, w = t >> 6;
    const int r16 = lane & 15, q4 = lane >> 4;
    const int n0 = blockIdx.x * 128, o0 = blockIdx.y * 128, b = blockIdx.z;
    const int wm = (w & 1) * 64, wn = (w >> 1) * 64;

    f32x4 acc[4][4];
#pragma unroll
    for (int i = 0; i < 4; ++i)
#pragma unroll
        for (int j = 0; j < 4; ++j) acc[i][j] = (f32x4){0.f, 0.f, 0.f, 0.f};

    const unsigned short* xtb = xt + (size_t)(b * NPIX + n0) * DIM;
    const int arow = t >> 3;
    const int aoff = (((t & 7) ^ (arow & 7)) * 16);
    const int fswz = (q4 ^ (r16 & 7)) << 3;

#pragma unroll
    for (int j = 0; j < 4; ++j) {
        int r = j * 32 + arow;
        gl_lds16((const char*)(xtb + (size_t)r * DIM) + aoff,
                 (char*)At[0] + j * 4096 + w * 1024);
        gl_lds16((const char*)(wqb + (size_t)(o0 + r) * DIM) + aoff,
                 (char*)Bt[0] + j * 4096 + w * 1024);
    }
    asm volatile("s_waitcnt vmcnt(0)" ::: "memory");
    __syncthreads();

    for (int kk = 0; kk < 8; ++kk) {
        const int cur = kk & 1;
        if (kk < 7) {
            const int c1 = (kk + 1) * 64, nxt = cur ^ 1;
#pragma unroll
            for (int j = 0; j < 4; ++j) {
                int r = j * 32 + arow;
                gl_lds16((const char*)(xtb + (size_t)r * DIM + c1) + aoff,
                         (char*)At[nxt] + j * 4096 + w * 1024);
                gl_lds16((const char*)(wqb + (size_t)(o0 + r) * DIM + c1) + aoff,
                         (char*)Bt[nxt] + j * 4096 + w * 1024);
            }
        }
#pragma unroll
        for (int ksx = 0; ksx < 2; ++ksx) {
            const int fo = fswz ^ (ksx << 5);
            bf16x8 af[4], bfr[4];
#pragma unroll
            for (int mt = 0; mt < 4; ++mt)
                af[mt] = *reinterpret_cast<const bf16x8*>(
                    &At[cur][(wm + mt * 16 + r16) * 64 + fo]);
#pragma unroll
            for (int nt = 0; nt < 4; ++nt)
                bfr[nt] = *reinterpret_cast<const bf16x8*>(
                    &Bt[cur][(wn + nt * 16 + r16) * 64 + fo]);
#pragma unroll
            for (int mt = 0; mt < 4; ++mt)
#pragma unroll
                for (int nt = 0; nt < 4; ++nt)
                    acc[mt][nt] = __builtin_amdgcn_mfma_f32_16x16x32_bf16(
                        af[mt], bfr[nt], acc[mt][nt], 0, 0, 0);
        }
        if (kk < 7) {
            asm volatile("s_waitcnt vmcnt(0)" ::: "memory");
            __syncthreads();
        }
    }

    const int sel = o0 >> 9;
#pragma unroll
    for (int nt = 0; nt < 4; ++nt) {
        const int o = o0 + wn + nt * 16 + r16;
        const float bs = bias[o];
        const int rem = o & 511, p = rem >> 6, d = rem & 63;
        const size_t bp = (size_t)(b * HEADS + p);
#pragma unroll
        for (int mt = 0; mt < 4; ++mt) {
            if (sel == 2) {
                ushort4 u;
                u.x = f2bf(acc[mt][nt][0] + bs);
                u.y = f2bf(acc[mt][nt][1] + bs);
                u.z = f2bf(acc[mt][nt][2] + bs);
                u.w = f2bf(acc[mt][nt][3] + bs);
                *(ushort4*)(vt + (bp * HD + d) * NPIX + n0 + wm + mt * 16 + q4 * 4) = u;
            } else {
#pragma unroll
                for (int reg = 0; reg < 4; ++reg) {
                    const int n = n0 + wm + mt * 16 + q4 * 4 + reg;
                    float val = acc[mt][nt][reg] + bs;
                    if (sel == 0) {   // q: fold SCALE * log2(e) for exp2 softmax
                        qs[(bp * NPIX + n) * HD + d] = f2bf(val * 0.1803368801111244f);
                    } else {
                        float rel = hrel[(n >> 5) * DIM + rem] + wrel[(n & 31) * DIM + rem];
                        ks[(bp * NPIX + n) * HD + d] = f2bf(val + rel);
                    }
                }
            }
        }
    }
}

// ---------------------------------------------------------------------------
// Kernel C: attention on 32x32x16 MFMA. Per wave: 32 q-rows (qcol=lane&31).
// S^T = K'.Q^T (A=K m=key, B=Q n=qrow): C col=qrow, rows=keys. PV A-frag
// (m=qrow, k=key, k=(h*8+j)) assembled with ONE shfl_xor(32) per dword +
// cndmask -- no bpermute, no LDS round-trip. Q read direct from global.
// K/V double-buffered (64 KB LDS, 2 blk/CU); XCD-locality block swizzle.
// ---------------------------------------------------------------------------
__global__ __launch_bounds__(256, 2) void k_attn(
        const unsigned short* __restrict__ qs, const unsigned short* __restrict__ ks,
        const unsigned short* __restrict__ vt, float* __restrict__ out) {
    __shared__ unsigned short Kt[2][128 * 64];     // 32 KB [key][d],  granule-swizzled
    __shared__ unsigned short Vt[2][64 * 128];     // 32 KB [d][key],  granule-swizzled
    const int t = threadIdx.x;
    const int lane = t & 63, w = t >> 6;
    const int lc = lane & 31, h = lane >> 5;
    // XCD-aware decode: same (b,p) for 8 consecutive blocks on one XCD
    const int gid = blockIdx.x;
    const int g = gid >> 3;
    const int bp_ = (gid & 7) * 32 + (g >> 3);
    const int qt = g & 7;
    const size_t bp = (size_t)bp_;
    const int b = bp_ >> 3, p = bp_ & 7;
    const unsigned short* kbase = ks + bp * NPIX * HD;
    const unsigned short* vbase = vt + bp * HD * NPIX;

    // staging address math (global side carries the granule swizzle)
    const int krow = t >> 3;
    const int koff = (((t & 7) ^ (krow & 7)) * 16);
    const int vrow = t >> 4;
    const int voff = (((t & 15) ^ (vrow & 7)) * 16);
    const int lsw = lc & 7;                       // read-side swizzle key

    // Q fragments direct from global: B[n=qrow=w*32+lc][k=h*8+j] per d-chunk
    const unsigned short* qrp = qs + (bp * NPIX + qt * 128 + w * 32 + lc) * HD;
    bf16x8 qf[4];
#pragma unroll
    for (int dk = 0; dk < 4; ++dk)
        qf[dk] = *reinterpret_cast<const bf16x8*>(qrp + dk * 16 + h * 8);

    // prologue: stage K(0), V(0)
#pragma unroll
    for (int j = 0; j < 4; ++j) {
        gl_lds16((const char*)kbase + (krow + j * 32) * 128 + koff,
                 (char*)Kt[0] + j * 4096 + w * 1024);
        gl_lds16((const char*)vbase + (vrow + j * 16) * 2048 + voff,
                 (char*)Vt[0] + j * 4096 + w * 1024);
    }
    asm volatile("s_waitcnt vmcnt(0)" ::: "memory");
    __syncthreads();

    f32x16 oacc[2];
    oacc[0] = (f32x16)(0.f);
    oacc[1] = (f32x16)(0.f);
    float lpart = 0.f;

    for (int kt = 0; kt < 8; ++kt) {
        const int cur = kt & 1;
        if (kt < 7) {   // prefetch next K/V tile
            const int nxt = cur ^ 1;
#pragma unroll
            for (int j = 0; j < 4; ++j) {
                gl_lds16((const char*)kbase + (kt + 1) * 16384 + (krow + j * 32) * 128 + koff,
                         (char*)Kt[nxt] + j * 4096 + w * 1024);
                gl_lds16((const char*)vbase + (vrow + j * 16) * 2048 + (kt + 1) * 256 + voff,
                         (char*)Vt[nxt] + j * 4096 + w * 1024);
            }
        }

        // ---- per key-tile T: S^T MFMA -> exp2 -> pack -> PV A-frags ------
        FragCast frag[4][2];
#pragma unroll
        for (int T = 0; T < 4; ++T) {
            f32x16 s = (f32x16)(0.f);
            const int krb = (T * 32 + lc) * 64;
#pragma unroll
            for (int dk = 0; dk < 4; ++dk) {
                bf16x8 ak = *reinterpret_cast<const bf16x8*>(
                    &Kt[cur][krb + (((dk * 2 + h) ^ lsw) * 8)]);
                s = __builtin_amdgcn_mfma_f32_32x32x16_bf16(ak, qf[dk], s, 0, 0, 0);
            }
            float e[16];
#pragma unroll
            for (int r = 0; r < 16; ++r) e[r] = exp2f(s[r]);
#pragma unroll
            for (int r = 0; r < 16; r += 4)
                lpart += ((e[r] + e[r + 1]) + (e[r + 2] + e[r + 3]));
            unsigned pk[8], xp[8];
#pragma unroll
            for (int j = 0; j < 8; ++j) pk[j] = pkbf(e[2 * j], e[2 * j + 1]);
#pragma unroll
            for (int j = 0; j < 8; ++j) xp[j] = __shfl_xor((int)pk[j], 32);
            // sub-chunk 0 (keys T*32 + 0..15), sub-chunk 1 (keys T*32 + 16..31)
            frag[T][0].i[0] = h ? xp[2] : pk[0];
            frag[T][0].i[1] = h ? xp[3] : pk[1];
            frag[T][0].i[2] = h ? pk[2] : xp[0];
            frag[T][0].i[3] = h ? pk[3] : xp[1];
            frag[T][1].i[0] = h ? xp[6] : pk[4];
            frag[T][1].i[1] = h ? xp[7] : pk[5];
            frag[T][1].i[2] = h ? pk[6] : xp[4];
            frag[T][1].i[3] = h ? pk[7] : xp[5];
        }

        // ---- PV: O[qrow][d] += P.V ---------------------------------------
#pragma unroll
        for (int c = 0; c < 8; ++c) {
            const int gv = ((c * 2 + h) ^ lsw) * 8;
#pragma unroll
            for (int nt = 0; nt < 2; ++nt) {
                bf16x8 bv = *reinterpret_cast<const bf16x8*>(
                    &Vt[cur][(nt * 32 + lc) * 128 + gv]);
                oacc[nt] = __builtin_amdgcn_mfma_f32_32x32x16_bf16(
                    frag[c >> 1][c & 1].v, bv, oacc[nt], 0, 0, 0);
            }
        }

        if (kt < 7) {
            asm volatile("s_waitcnt vmcnt(0)" ::: "memory");
            __syncthreads();
        }
    }

    // ---- normalize + store ------------------------------------------------
    lpart += __shfl_xor(lpart, 32);          // full l for qrow = w*32 + lc
    const float linv = 1.0f / lpart;
    float lb[4][4];
#pragma unroll
    for (int gg = 0; gg < 4; ++gg)
#pragma unroll
        for (int i = 0; i < 4; ++i)
            lb[gg][i] = __int_as_float(__builtin_amdgcn_ds_bpermute(
                (8 * gg + 4 * h + i) << 2, __float_as_int(linv)));
#pragma unroll
    for (int nt = 0; nt < 2; ++nt) {
        const int d = nt * 32 + lc;
        float* ob = out + ((size_t)(b * DIM + p * HD + d)) * NPIX + qt * 128 + w * 32;
#pragma unroll
        for (int gg = 0; gg < 4; ++gg) {
            float4 o4;
            o4.x = oacc[nt][4 * gg + 0] * lb[gg][0];
            o4.y = oacc[nt][4 * gg + 1] * lb[gg][1];
            o4.z = oacc[nt][4 * gg + 2] * lb[gg][2];
            o4.w = oacc[nt][4 * gg + 3] * lb[gg][3];
            *(float4*)(ob + 8 * gg + 4 * h) = o4;
        }
    }
}

// ---------------------------------------------------------------------------
extern "C" void kernel_launch(void* const* d_in, const int* in_sizes, int n_in,
                              void* d_out, int out_size, void* d_ws, size_t ws_size,
                              hipStream_t stream) {
    const float* x    = (const float*)d_in[0];
    const float* wq   = (const float*)d_in[1];
    const float* bias = (const float*)d_in[2];
    const float* hrel = (const float*)d_in[3];
    const float* wrel = (const float*)d_in[4];
    float* out = (float*)d_out;

    char* ws = (char*)d_ws;
    unsigned short* qs  = (unsigned short*)(ws);                 // 32 MB [b][p][n][d]
    unsigned short* ks  = (unsigned short*)(ws + 33554432u);     // 32 MB [b][p][n][d]
    unsigned short* vt  = (unsigned short*)(ws + 67108864u);     // 32 MB [b][p][d][n]
    unsigned short* xt  = (unsigned short*)d_out;                // 32 MB [b][n][c]
    unsigned short* wqb = (unsigned short*)((char*)d_out + 33554432u);  // 1.5 MB

    k_prep_w<<<dim3(768), 256, 0, stream>>>(wq, wqb);
    k_transpose<<<dim3(16, 8, 32), 256, 0, stream>>>(x, xt);
    k_qkv<<<dim3(8, 12, 32), 256, 0, stream>>>(xt, wqb, bias, hrel, wrel, qs, ks, vt);
    k_attn<<<dim3(2048), 256, 0, stream>>>(qs, ks, vt, out);
}

// Round 6
// 356.887 us; speedup vs baseline: 1.0598x; 1.0598x over previous
//
#include <hip/hip_runtime.h>
#include <hip/hip_bf16.h>

// Problem constants
#define NB    32
#define DIM   512
#define HEADS 8
#define HD    64
#define NPIX  1024   // H*W = 32*32

typedef __bf16 bf16x8 __attribute__((ext_vector_type(8)));
typedef float  f32x4  __attribute__((ext_vector_type(4)));
typedef float  f32x16 __attribute__((ext_vector_type(16)));

union FragCast { int i[4]; bf16x8 v; };

__device__ __forceinline__ unsigned short f2bf(float f) {
    union { float f; unsigned int i; } x; x.f = f;
    unsigned int r = x.i + 0x7fffu + ((x.i >> 16) & 1u);
    return (unsigned short)(r >> 16);
}
__device__ __forceinline__ unsigned pkbf(float a, float b) {   // low16=a, hi16=b
    __hip_bfloat162 h = __float22bfloat162_rn(make_float2(a, b));
    union { __hip_bfloat162 h; unsigned u; } c; c.h = h; return c.u;
}
__device__ __forceinline__ void gl_lds16(const void* g, void* l) {
    __builtin_amdgcn_global_load_lds(
        (const __attribute__((address_space(1))) unsigned int*)g,
        (__attribute__((address_space(3))) unsigned int*)l, 16, 0, 0);
}

// ---------------------------------------------------------------------------
// Kernel W: wq fp32 [1536][512] -> wqb bf16 (contiguous convert)
// ---------------------------------------------------------------------------
__global__ __launch_bounds__(256) void k_prep_w(
        const float* __restrict__ wq, unsigned short* __restrict__ wqb) {
    const int idx = (blockIdx.x * 256 + threadIdx.x) * 4;
    float4 f = *(const float4*)(wq + idx);
    ushort4 u;
    u.x = f2bf(f.x); u.y = f2bf(f.y); u.z = f2bf(f.z); u.w = f2bf(f.w);
    *(ushort4*)(wqb + idx) = u;
}

// ---------------------------------------------------------------------------
// Kernel A: x fp32 [b][c][n] -> xt bf16 [b][n][c]  (64x64 LDS-tiled transpose)
// HBM-bound at ~27 us (128 MB read + 32 MB write): already at roofline.
// ---------------------------------------------------------------------------
__global__ __launch_bounds__(256) void k_transpose(
        const float* __restrict__ x, unsigned short* __restrict__ xt) {
    __shared__ unsigned short tile[64][68];
    const int t = threadIdx.x;
    const int lane4 = t & 15, grp = t >> 4;
    const int n0 = blockIdx.x * 64, c0 = blockIdx.y * 64, b = blockIdx.z;
    const size_t xb = (size_t)b * DIM * NPIX;
#pragma unroll
    for (int i = 0; i < 4; ++i) {
        int c = c0 + grp + i * 16;
        float4 f = *(const float4*)(x + xb + (size_t)c * NPIX + n0 + lane4 * 4);
        ushort4 u;
        u.x = f2bf(f.x); u.y = f2bf(f.y); u.z = f2bf(f.z); u.w = f2bf(f.w);
        *(ushort4*)&tile[grp + i * 16][lane4 * 4] = u;
    }
    __syncthreads();
    const size_t xtb = (size_t)b * NPIX * DIM;
#pragma unroll
    for (int i = 0; i < 4; ++i) {
        int nr = grp + i * 16;
        ushort4 v;
        v.x = tile[lane4 * 4 + 0][nr];
        v.y = tile[lane4 * 4 + 1][nr];
        v.z = tile[lane4 * 4 + 2][nr];
        v.w = tile[lane4 * 4 + 3][nr];
        *(ushort4*)(xt + xtb + (size_t)(n0 + nr) * DIM + c0 + lane4 * 4) = v;
    }
}

// ---------------------------------------------------------------------------
// Kernel B: QKV GEMM, double-buffered LDS, XOR-swizzled tiles. 1D grid with
// XCD-locality decode: the 12 o-tile blocks sharing one xt A-tile are
// consecutive on one XCD -> xt tile L2-resident (was 12x L3 refetch).
// ---------------------------------------------------------------------------
__global__ __launch_bounds__(256, 2) void k_qkv(
        const unsigned short* __restrict__ xt, const unsigned short* __restrict__ wqb,
        const float* __restrict__ bias,
        const float* __restrict__ hrel, const float* __restrict__ wrel,
        unsigned short* __restrict__ qs, unsigned short* __restrict__ ks,
        unsigned short* __restrict__ vt) {
    __shared__ unsigned short At[2][128 * 64];
    __shared__ unsigned short Bt[2][128 * 64];
    const int t = threadIdx.x;
    const int lane = t & 63, w = t >> 6;
    const int r16 = lane & 15, q4 = lane >> 4;
    // XCD decode: gid&7 = XCD; per XCD, y (o-tile) innermost over 32 (x,b)
    const int gid = blockIdx.x;
    const int u = gid >> 3;
    const int y = u % 12;
    const int xz = (gid & 7) * 32 + u / 12;
    const int n0 = (xz & 7) * 128, o0 = y * 128, b = xz >> 3;
    const int wm = (w & 1) * 64, wn = (w >> 1) * 64;

    f32x4 acc[4][4];
#pragma unroll
    for (int i = 0; i < 4; ++i)
#pragma unroll
        for (int j = 0; j < 4; ++j) acc[i][j] = (f32x4){0.f, 0.f, 0.f, 0.f};

    const unsigned short* xtb = xt + (size_t)(b * NPIX + n0) * DIM;
    const int arow = t >> 3;
    const int aoff = (((t & 7) ^ (arow & 7)) * 16);
    const int fswz = (q4 ^ (r16 & 7)) << 3;

#pragma unroll
    for (int j = 0; j < 4; ++j) {
        int r = j * 32 + arow;
        gl_lds16((const char*)(xtb + (size_t)r * DIM) + aoff,
                 (char*)At[0] + j * 4096 + w * 1024);
        gl_lds16((const char*)(wqb + (size_t)(o0 + r) * DIM) + aoff,
                 (char*)Bt[0] + j * 4096 + w * 1024);
    }
    asm volatile("s_waitcnt vmcnt(0)" ::: "memory");
    __syncthreads();

    for (int kk = 0; kk < 8; ++kk) {
        const int cur = kk & 1;
        if (kk < 7) {
            const int c1 = (kk + 1) * 64, nxt = cur ^ 1;
#pragma unroll
            for (int j = 0; j < 4; ++j) {
                int r = j * 32 + arow;
                gl_lds16((const char*)(xtb + (size_t)r * DIM + c1) + aoff,
                         (char*)At[nxt] + j * 4096 + w * 1024);
                gl_lds16((const char*)(wqb + (size_t)(o0 + r) * DIM + c1) + aoff,
                         (char*)Bt[nxt] + j * 4096 + w * 1024);
            }
        }
#pragma unroll
        for (int ksx = 0; ksx < 2; ++ksx) {
            const int fo = fswz ^ (ksx << 5);
            bf16x8 af[4], bfr[4];
#pragma unroll
            for (int mt = 0; mt < 4; ++mt)
                af[mt] = *reinterpret_cast<const bf16x8*>(
                    &At[cur][(wm + mt * 16 + r16) * 64 + fo]);
#pragma unroll
            for (int nt = 0; nt < 4; ++nt)
                bfr[nt] = *reinterpret_cast<const bf16x8*>(
                    &Bt[cur][(wn + nt * 16 + r16) * 64 + fo]);
#pragma unroll
            for (int mt = 0; mt < 4; ++mt)
#pragma unroll
                for (int nt = 0; nt < 4; ++nt)
                    acc[mt][nt] = __builtin_amdgcn_mfma_f32_16x16x32_bf16(
                        af[mt], bfr[nt], acc[mt][nt], 0, 0, 0);
        }
        if (kk < 7) {
            asm volatile("s_waitcnt vmcnt(0)" ::: "memory");
            __syncthreads();
        }
    }

    const int sel = o0 >> 9;
#pragma unroll
    for (int nt = 0; nt < 4; ++nt) {
        const int o = o0 + wn + nt * 16 + r16;
        const float bs = bias[o];
        const int rem = o & 511, p = rem >> 6, d = rem & 63;
        const size_t bp = (size_t)(b * HEADS + p);
#pragma unroll
        for (int mt = 0; mt < 4; ++mt) {
            if (sel == 2) {
                ushort4 u4;
                u4.x = f2bf(acc[mt][nt][0] + bs);
                u4.y = f2bf(acc[mt][nt][1] + bs);
                u4.z = f2bf(acc[mt][nt][2] + bs);
                u4.w = f2bf(acc[mt][nt][3] + bs);
                *(ushort4*)(vt + (bp * HD + d) * NPIX + n0 + wm + mt * 16 + q4 * 4) = u4;
            } else {
#pragma unroll
                for (int reg = 0; reg < 4; ++reg) {
                    const int n = n0 + wm + mt * 16 + q4 * 4 + reg;
                    float val = acc[mt][nt][reg] + bs;
                    if (sel == 0) {   // q: fold SCALE * log2(e) for exp2 softmax
                        qs[(bp * NPIX + n) * HD + d] = f2bf(val * 0.1803368801111244f);
                    } else {
                        float rel = hrel[(n >> 5) * DIM + rem] + wrel[(n & 31) * DIM + rem];
                        ks[(bp * NPIX + n) * HD + d] = f2bf(val + rel);
                    }
                }
            }
        }
    }
}

// ---------------------------------------------------------------------------
// Kernel C: attention, 32x32x16 MFMA. KEY CHANGE: K rows are staged with the
// sigma-permutation (swap 4-row groups {4..7}<->{8..11} mod 16) so each
// lane's packed exp2 registers ARE the PV A-fragment in order -- zero
// shuffles, zero selects. K dbuf (32K) + V single (16K) = 48 KB -> 3 blk/CU.
// V staged per-iter, latency hidden behind S-MFMA+exp2 (mid vmcnt+barrier).
// ---------------------------------------------------------------------------
__global__ __launch_bounds__(256, 3) void k_attn(
        const unsigned short* __restrict__ qs, const unsigned short* __restrict__ ks,
        const unsigned short* __restrict__ vt, float* __restrict__ out) {
    __shared__ unsigned short Kt[2][128 * 64];     // 32 KB [key][d], sigma+granule swizzle
    __shared__ unsigned short Vt[64 * 128];        // 16 KB [d][key], granule swizzle
    const int t = threadIdx.x;
    const int lane = t & 63, w = t >> 6;
    const int lc = lane & 31, h = lane >> 5;
    // XCD-aware decode: same (b,p) for 8 consecutive blocks on one XCD
    const int gid = blockIdx.x;
    const int g = gid >> 3;
    const int bp_ = (gid & 7) * 32 + (g >> 3);
    const int qt = g & 7;
    const size_t bp = (size_t)bp_;
    const int b = bp_ >> 3, p = bp_ & 7;
    const unsigned short* kbase = ks + bp * NPIX * HD;
    const unsigned short* vbase = vt + bp * HD * NPIX;

    // staging addresses (global side carries sigma + granule swizzle)
    const int krow = t >> 3;
    const int ksig = (((krow >> 2) ^ (krow >> 3)) & 1) ? 12 : 0;
    const int skrow = krow ^ ksig;                       // sigma source row
    const int koff = (((t & 7) ^ (krow & 7)) * 16);
    const int vrow = t >> 4;
    const int voff = (((t & 15) ^ (vrow & 7)) * 16);
    const int lsw = lc & 7;                              // read-side swizzle key

    // Q fragments direct from global: B[n=qrow=w*32+lc][k=h*8+j] per d-chunk
    const unsigned short* qrp = qs + (bp * NPIX + qt * 128 + w * 32 + lc) * HD;
    bf16x8 qf[4];
#pragma unroll
    for (int dk = 0; dk < 4; ++dk)
        qf[dk] = *reinterpret_cast<const bf16x8*>(qrp + dk * 16 + h * 8);

    // prologue: stage K(0)
#pragma unroll
    for (int j = 0; j < 4; ++j)
        gl_lds16((const char*)kbase + (skrow + j * 32) * 128 + koff,
                 (char*)Kt[0] + j * 4096 + w * 1024);
    asm volatile("s_waitcnt vmcnt(0)" ::: "memory");
    __syncthreads();

    f32x16 oacc[2];
    oacc[0] = (f32x16)(0.f);
    oacc[1] = (f32x16)(0.f);
    float lpart = 0.f;

    for (int kt = 0; kt < 8; ++kt) {
        const int cur = kt & 1;
        // stage V(kt) into the single V buffer (all waves past prior barrier)
#pragma unroll
        for (int j = 0; j < 4; ++j)
            gl_lds16((const char*)vbase + (vrow + j * 16) * 2048 + kt * 256 + voff,
                     (char*)Vt + j * 4096 + w * 1024);
        if (kt < 7) {   // prefetch K(kt+1)
            const int nxt = cur ^ 1;
#pragma unroll
            for (int j = 0; j < 4; ++j)
                gl_lds16((const char*)kbase + (kt + 1) * 16384 + (skrow + j * 32) * 128 + koff,
                         (char*)Kt[nxt] + j * 4096 + w * 1024);
        }

        // ---- S^T = K'.Q^T per 32-key tile, exp2, pack ---------------------
        unsigned pk[4][8];
#pragma unroll
        for (int T = 0; T < 4; ++T) {
            f32x16 s = (f32x16)(0.f);
            const int krb = (T * 32 + lc) * 64;
#pragma unroll
            for (int dk = 0; dk < 4; ++dk) {
                bf16x8 ak = *reinterpret_cast<const bf16x8*>(
                    &Kt[cur][krb + (((dk * 2 + h) ^ lsw) * 8)]);
                s = __builtin_amdgcn_mfma_f32_32x32x16_bf16(ak, qf[dk], s, 0, 0, 0);
            }
            float e[16];
#pragma unroll
            for (int r = 0; r < 16; ++r) e[r] = exp2f(s[r]);
#pragma unroll
            for (int r = 0; r < 16; r += 4)
                lpart += ((e[r] + e[r + 1]) + (e[r + 2] + e[r + 3]));
#pragma unroll
            for (int j = 0; j < 8; ++j) pk[T][j] = pkbf(e[2 * j], e[2 * j + 1]);
        }

        // wait own V loads (4 newest-issued K may stay outstanding), sync
        if (kt < 7) { asm volatile("s_waitcnt vmcnt(4)" ::: "memory"); }
        else        { asm volatile("s_waitcnt vmcnt(0)" ::: "memory"); }
        __syncthreads();

        // ---- PV: A-frag = lane's own pk registers (sigma made it so) ------
#pragma unroll
        for (int c = 0; c < 8; ++c) {
            FragCast fa;
            fa.i[0] = (int)pk[c >> 1][(c & 1) * 4 + 0];
            fa.i[1] = (int)pk[c >> 1][(c & 1) * 4 + 1];
            fa.i[2] = (int)pk[c >> 1][(c & 1) * 4 + 2];
            fa.i[3] = (int)pk[c >> 1][(c & 1) * 4 + 3];
            const int gv = ((c * 2 + h) ^ lsw) * 8;
#pragma unroll
            for (int nt = 0; nt < 2; ++nt) {
                bf16x8 bv = *reinterpret_cast<const bf16x8*>(
                    &Vt[(nt * 32 + lc) * 128 + gv]);
                oacc[nt] = __builtin_amdgcn_mfma_f32_32x32x16_bf16(
                    fa.v, bv, oacc[nt], 0, 0, 0);
            }
        }

        if (kt < 7) {   // K(kt+1) landed for all waves; V readers done
            asm volatile("s_waitcnt vmcnt(0)" ::: "memory");
            __syncthreads();
        }
    }

    // ---- normalize + store (verified R5 mapping) --------------------------
    lpart += __shfl_xor(lpart, 32);          // full l for qrow = w*32 + lc
    const float linv = 1.0f / lpart;
    float lb[4][4];
#pragma unroll
    for (int gg = 0; gg < 4; ++gg)
#pragma unroll
        for (int i = 0; i < 4; ++i)
            lb[gg][i] = __int_as_float(__builtin_amdgcn_ds_bpermute(
                (8 * gg + 4 * h + i) << 2, __float_as_int(linv)));
#pragma unroll
    for (int nt = 0; nt < 2; ++nt) {
        const int d = nt * 32 + lc;
        float* ob = out + ((size_t)(b * DIM + p * HD + d)) * NPIX + qt * 128 + w * 32;
#pragma unroll
        for (int gg = 0; gg < 4; ++gg) {
            float4 o4;
            o4.x = oacc[nt][4 * gg + 0] * lb[gg][0];
            o4.y = oacc[nt][4 * gg + 1] * lb[gg][1];
            o4.z = oacc[nt][4 * gg + 2] * lb[gg][2];
            o4.w = oacc[nt][4 * gg + 3] * lb[gg][3];
            *(float4*)(ob + 8 * gg + 4 * h) = o4;
        }
    }
}

// ---------------------------------------------------------------------------
extern "C" void kernel_launch(void* const* d_in, const int* in_sizes, int n_in,
                              void* d_out, int out_size, void* d_ws, size_t ws_size,
                              hipStream_t stream) {
    const float* x    = (const float*)d_in[0];
    const float* wq   = (const float*)d_in[1];
    const float* bias = (const float*)d_in[2];
    const float* hrel = (const float*)d_in[3];
    const float* wrel = (const float*)d_in[4];
    float* out = (float*)d_out;

    char* ws = (char*)d_ws;
    unsigned short* qs  = (unsigned short*)(ws);                 // 32 MB [b][p][n][d]
    unsigned short* ks  = (unsigned short*)(ws + 33554432u);     // 32 MB [b][p][n][d]
    unsigned short* vt  = (unsigned short*)(ws + 67108864u);     // 32 MB [b][p][d][n]
    unsigned short* xt  = (unsigned short*)d_out;                // 32 MB [b][n][c]
    unsigned short* wqb = (unsigned short*)((char*)d_out + 33554432u);  // 1.5 MB

    k_prep_w<<<dim3(768), 256, 0, stream>>>(wq, wqb);
    k_transpose<<<dim3(16, 8, 32), 256, 0, stream>>>(x, xt);
    k_qkv<<<dim3(3072), 256, 0, stream>>>(xt, wqb, bias, hrel, wrel, qs, ks, vt);
    k_attn<<<dim3(2048), 256, 0, stream>>>(qs, ks, vt, out);
}